// Round 4
// baseline (4227.042 us; speedup 1.0000x reference)
//
#include <hip/hip_runtime.h>
#include <hip/hip_cooperative_groups.h>
#include <math.h>
#include <stdint.h>

namespace cg = cooperative_groups;

// Problem constants
#define B_ 512
#define D_ 1024
#define H_ 1024
#define T_ 48
#define NG 4096      // 4*H gate columns
#define K2 2048      // D + H concatenated K

typedef _Float16 half8 __attribute__((ext_vector_type(8)));
typedef float f32x4 __attribute__((ext_vector_type(4)));

// Async global->LDS, 16B per lane (used only in gemm_pool).
__device__ __forceinline__ void cp16(const void* g, void* l) {
  __builtin_amdgcn_global_load_lds(
      (__attribute__((address_space(1))) const unsigned int*)(uintptr_t)g,
      (__attribute__((address_space(3))) unsigned int*)(uintptr_t)l, 16, 0, 0);
}

__device__ __forceinline__ float sigmoidf_(float x) { return 1.0f / (1.0f + expf(-x)); }

// ---------------------------------------------------------------------------
// Prep: W_cat[j][0:1024]=W_ih[j][0:1024], W_cat[j][1024:2048]=W_hh[j][:]  (f16)
//       Wp[j][k] = W_ih[j][1024+k]                                        (f16)
// ---------------------------------------------------------------------------
__global__ void prep_w(const float* __restrict__ W_ih, const float* __restrict__ W_hh,
                       _Float16* __restrict__ Wcat, _Float16* __restrict__ Wp) {
  int idx = blockIdx.x * 256 + threadIdx.x;
  const int n1 = NG * K2;  // 8388608
  if (idx < n1) {
    int j = idx >> 11, k = idx & 2047;
    float v = (k < D_) ? W_ih[j * K2 + k] : W_hh[j * H_ + (k - D_)];
    Wcat[idx] = (_Float16)v;
  } else {
    int i2 = idx - n1;
    if (i2 < NG * D_) {
      int j = i2 >> 10, k = i2 & 1023;
      Wp[i2] = (_Float16)W_ih[j * K2 + D_ + k];
    }
  }
}

// ---------------------------------------------------------------------------
// Pool: pooled[b][d]; also dh->f16 (t>=1)
// ---------------------------------------------------------------------------
__global__ void pool_conv(const float* __restrict__ dh, const int* __restrict__ caps,
                          _Float16* __restrict__ dh16, _Float16* __restrict__ pooled16) {
  int tid = blockIdx.x * 256 + threadIdx.x;  // b*1024 + d
  int b = tid >> 10;
  float sum = 0.0f, cnt = 0.0f;
  for (int t = 0; t < T_; ++t) {
    int cap = caps[t * B_ + b];
    float v = dh[(size_t)t * (B_ * D_) + tid];
    if (cap != 0 && cap != 2) { sum += v; cnt += 1.0f; }
    if (t >= 1) dh16[(size_t)t * (B_ * D_) + tid] = (_Float16)v;
  }
  pooled16[tid] = (_Float16)(sum / cnt);
}

// ---------------------------------------------------------------------------
// Init: hA=0, c=0, feats[:,0,:]=0
// ---------------------------------------------------------------------------
__global__ void init_zero(_Float16* __restrict__ hA, float* __restrict__ c,
                          float* __restrict__ out) {
  int tid = blockIdx.x * 256 + threadIdx.x;  // < 524288
  hA[tid] = (_Float16)0.0f;
  c[tid] = 0.0f;
  int b = tid >> 10, d = tid & 1023;
  out[(size_t)b * (T_ * H_) + d] = 0.0f;
}

// ---------------------------------------------------------------------------
// Xc[b][n] = pooled[b]·Wp[n] + b_ih[n] + b_hh[n]   (64x128 tile, 16x16x32 MFMA)
// ---------------------------------------------------------------------------
__global__ __launch_bounds__(256) void gemm_pool(
    const _Float16* __restrict__ A, const _Float16* __restrict__ Wp,
    const float* __restrict__ b_ih, const float* __restrict__ b_hh,
    float* __restrict__ Xc) {
  __shared__ __align__(16) _Float16 sA[64 * 32];
  __shared__ __align__(16) _Float16 sB[128 * 32];
  const int tid = threadIdx.x;
  const int wave = tid >> 6, lane = tid & 63;
  const int quad = lane >> 4, l16 = lane & 15;
  const int wm = wave & 1, wn = wave >> 1;
  const int n0 = blockIdx.x * 128;
  const int b0 = blockIdx.y * 64;
  const int rS = tid >> 2, cS = tid & 3;

  f32x4 acc[2][4] = {};
  for (int k0 = 0; k0 < 1024; k0 += 32) {
    cp16(A + (size_t)(b0 + rS) * 1024 + k0 + cS * 8, sA + wave * 512);
    cp16(Wp + (size_t)(n0 + rS) * 1024 + k0 + cS * 8, sB + wave * 512);
    cp16(Wp + (size_t)(n0 + 64 + rS) * 1024 + k0 + cS * 8, sB + 2048 + wave * 512);
    __syncthreads();
    half8 a[2], bfr[4];
#pragma unroll
    for (int m = 0; m < 2; ++m)
      a[m] = *(const half8*)(sA + (wm * 32 + m * 16 + l16) * 32 + quad * 8);
#pragma unroll
    for (int n = 0; n < 4; ++n)
      bfr[n] = *(const half8*)(sB + (wn * 64 + n * 16 + l16) * 32 + quad * 8);
#pragma unroll
    for (int m = 0; m < 2; ++m)
#pragma unroll
      for (int n = 0; n < 4; ++n)
        acc[m][n] = __builtin_amdgcn_mfma_f32_16x16x32_f16(a[m], bfr[n], acc[m][n], 0, 0, 0);
    __syncthreads();
  }
#pragma unroll
  for (int m = 0; m < 2; ++m) {
#pragma unroll
    for (int n = 0; n < 4; ++n) {
      int nn = n0 + wn * 64 + n * 16 + l16;
      float bias = b_ih[nn] + b_hh[nn];
#pragma unroll
      for (int r = 0; r < 4; ++r) {
        int bb = b0 + wm * 32 + m * 16 + quad * 4 + r;
        Xc[(size_t)bb * NG + nn] = acc[m][n][r] + bias;
      }
    }
  }
}

// ---------------------------------------------------------------------------
// Fallback per-step LSTM (round-2 verified kernel, unchanged).
// ---------------------------------------------------------------------------
__global__ __launch_bounds__(256) void lstm_step(
    const _Float16* __restrict__ dh16, const _Float16* __restrict__ Wcat,
    const float* __restrict__ Xc, const _Float16* __restrict__ h_prev,
    _Float16* __restrict__ h_next, float* __restrict__ c,
    float* __restrict__ out, int t) {
  __shared__ __align__(16) _Float16 sA[64 * 32];
  __shared__ __align__(16) _Float16 sB[128 * 32];
  const int tid = threadIdx.x;
  const int wave = tid >> 6, lane = tid & 63;
  const int quad = lane >> 4, l16 = lane & 15;
  const int wm = wave & 1, wn = wave >> 1;
  const int j0 = blockIdx.x * 32;
  const int b0 = blockIdx.y * 64;
  const int rS = tid >> 2, cS = tid & 3;

  const _Float16* dhT = dh16 + (size_t)t * (B_ * D_);
  const int jr0 = (((rS >> 4) & 3) << 10) + j0 + (rS & 15);
  const int jr1 = jr0 + 16;
  const int aRow = b0 + rS;

  f32x4 acc[2][4] = {};
  for (int k0 = 0; k0 < K2; k0 += 32) {
    const _Float16* aSrc = (k0 < 1024)
        ? (dhT + (size_t)aRow * 1024 + k0 + cS * 8)
        : (h_prev + (size_t)aRow * 1024 + (k0 - 1024) + cS * 8);
    cp16(aSrc, sA + wave * 512);
    cp16(Wcat + (size_t)jr0 * K2 + k0 + cS * 8, sB + wave * 512);
    cp16(Wcat + (size_t)jr1 * K2 + k0 + cS * 8, sB + 2048 + wave * 512);
    __syncthreads();
    half8 a[2], bfr[4];
#pragma unroll
    for (int m = 0; m < 2; ++m)
      a[m] = *(const half8*)(sA + (wm * 32 + m * 16 + l16) * 32 + quad * 8);
#pragma unroll
    for (int n = 0; n < 4; ++n)
      bfr[n] = *(const half8*)(sB + (wn * 64 + n * 16 + l16) * 32 + quad * 8);
#pragma unroll
    for (int m = 0; m < 2; ++m)
#pragma unroll
      for (int n = 0; n < 4; ++n)
        acc[m][n] = __builtin_amdgcn_mfma_f32_16x16x32_f16(a[m], bfr[n], acc[m][n], 0, 0, 0);
    __syncthreads();
  }

  const int col = j0 + wn * 16 + l16;
#pragma unroll
  for (int m = 0; m < 2; ++m) {
#pragma unroll
    for (int r = 0; r < 4; ++r) {
      int bb = b0 + wm * 32 + m * 16 + quad * 4 + r;
      const float* xb = Xc + (size_t)bb * NG + col;
      float iv = acc[m][0][r] + xb[0];
      float fv = acc[m][1][r] + xb[1024];
      float gv = acc[m][2][r] + xb[2048];
      float ov = acc[m][3][r] + xb[3072];
      float ig = sigmoidf_(iv), fg = sigmoidf_(fv), og = sigmoidf_(ov);
      float gg = tanhf(gv);
      size_t ci = (size_t)bb * H_ + col;
      float cn = fg * c[ci] + ig * gg;
      c[ci] = cn;
      float hv = og * tanhf(cn);
      h_next[ci] = (_Float16)hv;
      out[(size_t)bb * (T_ * H_) + (size_t)t * H_ + col] = hv;
    }
  }
}

// ---------------------------------------------------------------------------
// Persistent LSTM: 256 blocks (= 64 col-groups x 4 batch-groups), cooperative.
// Dynamic LDS (152 KB): sWhh resident 64x1024 f16 packed, sA/sWx dbuf.
// Fragment layouts are the 16x16x32 mappings verified in rounds 1-2:
//   A/B frag: idx=lane&15, k=quad*8+j (contiguous 16B per lane in packed LDS)
//   C/D: col=lane&15, row=quad*4+reg
// Packed line for element (idx i in tile, k): line = tilebase + (k>>3 mod4)*16 + i,
// 8 f16 per line; a frag read is 64 consecutive lines = lane*16B. Conflict-free.
// ---------------------------------------------------------------------------
__global__ __launch_bounds__(256, 1) void lstm_persist(
    const _Float16* __restrict__ dh16, const _Float16* __restrict__ Wcat,
    const float* __restrict__ Xc, _Float16* __restrict__ hA,
    _Float16* __restrict__ hB, float* __restrict__ out) {
  extern __shared__ __align__(16) _Float16 smem[];
  _Float16* sWhh = smem;                  // 65536 halfs = 128 KB: 32 kc x 4 gates x 512
  _Float16* sA   = smem + 65536;          // 2 x 4096 halfs = 16 KB: 8 mt x 512
  _Float16* sWx  = smem + 65536 + 8192;   // 2 x 2048 halfs = 8 KB: 4 gates x 512

  const int tid = threadIdx.x;
  const int lane = tid & 63, wv = tid >> 6;
  const int quad = lane >> 4, l16 = lane & 15;
  const int jg = blockIdx.x & 63, bgp = blockIdx.x >> 6;
  const int hc0 = jg * 16, b0 = bgp * 128;
  cg::grid_group grid = cg::this_grid();

  // ---- resident Whh (k 1024..2047 of Wcat rows for this column group)
  {
    int n = tid >> 2, q = tid & 3;             // n: packed gate-row 0..63
    int gate = n >> 4, cc = n & 15;
    const _Float16* src = Wcat + (size_t)(gate * 1024 + hc0 + cc) * K2 + 1024 + q * 256;
#pragma unroll 4
    for (int i = 0; i < 32; ++i) {
      int k = q * 256 + i * 8;
      half8 v = *(const half8*)(src + i * 8);
      int line = ((k >> 5) * 4 + gate) * 64 + ((k >> 3) & 3) * 16 + cc;
      *(half8*)(sWhh + line * 8) = v;
    }
  }

  float creg[2][4];
#pragma unroll
  for (int m = 0; m < 2; ++m)
#pragma unroll
    for (int r = 0; r < 4; ++r) creg[m][r] = 0.0f;

  // staging roles
  const int aM = tid >> 1, aK = (tid & 1) * 16;   // A: rows 0..127, 2 half8 each
  const int aLine0 = (aM >> 4) * 64 + (aK >> 3) * 16 + (aM & 15);
  const int aLine1 = aLine0 + 16;
  const int wN = tid >> 2, wq = tid & 3;          // Wx: 64 gate rows, 1 half8 each
  const _Float16* wSrc =
      Wcat + (size_t)((wN >> 4) * 1024 + hc0 + (wN & 15)) * K2 + wq * 8;
  const int wLine = (wN >> 4) * 64 + wq * 16 + (wN & 15);

  __syncthreads();

  for (int t = 1; t < T_; ++t) {
    const _Float16* __restrict__ hprev = (t & 1) ? hA : hB;
    _Float16* __restrict__ hnext = (t & 1) ? hB : hA;
    const _Float16* __restrict__ dhT = dh16 + (size_t)t * (B_ * D_);
    f32x4 acc[2][4] = {};

    {  // prologue: stage chunk 0
      const _Float16* asrc = dhT + (size_t)(b0 + aM) * 1024 + aK;
      half8 va0 = *(const half8*)(asrc);
      half8 va1 = *(const half8*)(asrc + 8);
      half8 vw = *(const half8*)(wSrc);
      *(half8*)(sA + aLine0 * 8) = va0;
      *(half8*)(sA + aLine1 * 8) = va1;
      *(half8*)(sWx + wLine * 8) = vw;
    }
    __syncthreads();

    for (int kc = 0; kc < 64; ++kc) {  // chunk = 32 k
      const int cur = kc & 1, nxt = cur ^ 1;
      const bool haveNext = (kc < 63);
      half8 va0, va1, vw;
      if (haveNext) {
        const int k0n = (kc + 1) * 32;
        const _Float16* asrc = (k0n < 1024)
            ? dhT + (size_t)(b0 + aM) * 1024 + k0n + aK
            : hprev + (size_t)(b0 + aM) * 1024 + (k0n - 1024) + aK;
        va0 = *(const half8*)(asrc);
        va1 = *(const half8*)(asrc + 8);
        if (k0n < 1024) vw = *(const half8*)(wSrc + k0n);
      }
      half8 a[2], bfr[4];
#pragma unroll
      for (int m = 0; m < 2; ++m)
        a[m] = *(const half8*)(sA + cur * 4096 + ((wv * 2 + m) * 64 + lane) * 8);
      if (kc < 32) {
#pragma unroll
        for (int g = 0; g < 4; ++g)
          bfr[g] = *(const half8*)(sWx + cur * 2048 + (g * 64 + lane) * 8);
      } else {
#pragma unroll
        for (int g = 0; g < 4; ++g)
          bfr[g] = *(const half8*)(sWhh + (((kc - 32) * 4 + g) * 64 + lane) * 8);
      }
#pragma unroll
      for (int m = 0; m < 2; ++m)
#pragma unroll
        for (int g = 0; g < 4; ++g)
          acc[m][g] = __builtin_amdgcn_mfma_f32_16x16x32_f16(a[m], bfr[g], acc[m][g], 0, 0, 0);
      if (haveNext) {
        *(half8*)(sA + nxt * 4096 + aLine0 * 8) = va0;
        *(half8*)(sA + nxt * 4096 + aLine1 * 8) = va1;
        if ((kc + 1) < 32) *(half8*)(sWx + nxt * 2048 + wLine * 8) = vw;
      }
      __syncthreads();
    }

    // epilogue (same mapping as verified lstm_step): col = hc0+l16, gates = n-tiles
    const int col = hc0 + l16;
#pragma unroll
    for (int m = 0; m < 2; ++m) {
#pragma unroll
      for (int r = 0; r < 4; ++r) {
        int brow = b0 + (wv * 2 + m) * 16 + quad * 4 + r;
        const float* xb = Xc + (size_t)brow * NG + col;
        float iv = acc[m][0][r] + xb[0];
        float fv = acc[m][1][r] + xb[1024];
        float gv = acc[m][2][r] + xb[2048];
        float ov = acc[m][3][r] + xb[3072];
        float ig = sigmoidf_(iv), fg = sigmoidf_(fv), og = sigmoidf_(ov);
        float cn = fg * creg[m][r] + ig * tanhf(gv);
        creg[m][r] = cn;
        float hv = og * tanhf(cn);
        hnext[(size_t)brow * H_ + col] = (_Float16)hv;
        out[(size_t)brow * (T_ * H_) + (size_t)t * H_ + col] = hv;
      }
    }
    __threadfence();
    grid.sync();
  }
}

// ---------------------------------------------------------------------------
extern "C" void kernel_launch(void* const* d_in, const int* in_sizes, int n_in,
                              void* d_out, int out_size, void* d_ws, size_t ws_size,
                              hipStream_t stream) {
  (void)in_sizes; (void)n_in; (void)out_size; (void)ws_size;
  const float* dh   = (const float*)d_in[0];
  const int*   caps = (const int*)d_in[2];
  const float* W_ih = (const float*)d_in[3];
  const float* W_hh = (const float*)d_in[4];
  const float* b_ih = (const float*)d_in[5];
  const float* b_hh = (const float*)d_in[6];
  float* out = (float*)d_out;

  char* ws = (char*)d_ws;
  _Float16* Wcat  = (_Float16*)(ws);              // 16,777,216 B
  _Float16* Wp    = (_Float16*)(ws + 16777216);   //  8,388,608 B
  _Float16* dh16  = (_Float16*)(ws + 25165824);   // 50,331,648 B
  _Float16* pld16 = (_Float16*)(ws + 75497472);   //  1,048,576 B
  float*    Xc    = (float*)   (ws + 76546048);   //  8,388,608 B
  _Float16* hA    = (_Float16*)(ws + 84934656);   //  1,048,576 B
  _Float16* hB    = (_Float16*)(ws + 85983232);   //  1,048,576 B
  float*    c     = (float*)   (ws + 87031808);   //  2,097,152 B  (end ~89.1 MB)

  prep_w<<<49152, 256, 0, stream>>>(W_ih, W_hh, Wcat, Wp);
  pool_conv<<<2048, 256, 0, stream>>>(dh, caps, dh16, pld16);
  init_zero<<<2048, 256, 0, stream>>>(hA, c, out);
  gemm_pool<<<dim3(32, 8), 256, 0, stream>>>(pld16, Wp, b_ih, b_hh, Xc);

  const int smemBytes = (65536 + 8192 + 4096) * 2;  // 155648 B = 152 KB
  (void)hipFuncSetAttribute((const void*)lstm_persist,
                            hipFuncAttributeMaxDynamicSharedMemorySize, smemBytes);
  void* args[] = {(void*)&dh16, (void*)&Wcat, (void*)&Xc,
                  (void*)&hA, (void*)&hB, (void*)&out};
  hipError_t err = hipLaunchCooperativeKernel((void*)lstm_persist, dim3(256),
                                              dim3(256), args, smemBytes, stream);
  if (err != hipSuccess) {
    // Deterministic fallback: verified round-2 per-step loop (same work every call).
    for (int t = 1; t < T_; ++t) {
      const _Float16* hp = (t & 1) ? hA : hB;
      _Float16*       hn = (t & 1) ? hB : hA;
      lstm_step<<<dim3(32, 8), 256, 0, stream>>>(dh16, Wcat, Xc, hp, hn, c, out, t);
    }
  }
}